// Round 1
// baseline (165.668 us; speedup 1.0000x reference)
//
#include <hip/hip_runtime.h>
#include <stdint.h>

#define N_NODES 2048
#define N_BATCH 4
#define ROWS_PER_BLOCK 8
#define THREADS 512   // 8 waves, one row per wave

__device__ __forceinline__ uint32_t bf16rn(float x) {
    uint32_t u = __float_as_uint(x);
    u += 0x7fffu + ((u >> 16) & 1u);
    return u >> 16;
}

// LDS = 32 KB table -> 4 blocks/CU (thread-cap), 32 waves/CU.
// __launch_bounds__(512, 8): 8 waves/SIMD -> VGPR capped at 64; we now
// deliberately SPEND that budget on in-flight loads (prev kernel sat at 24
// VGPR with zero memory-level parallelism -> vmcnt-stall-bound at 2.8 TB/s).
__global__ __launch_bounds__(THREADS, 8) void kuramoto_kernel(
    const float* __restrict__ theta,
    const float* __restrict__ gamma,
    const float* __restrict__ W,
    const float* __restrict__ alpha,
    float* __restrict__ out)
{
    // SoA by d: tbl[d][j] = (bf16(cos th_jd)<<16) | bf16(sin th_jd)
    // Lane owns 4 consecutive j -> per-d read is ds_read_b128 at lane
    // stride 16B = the conflict-free pattern (AoS would be 8-way).
    __shared__ uint32_t tbl[4][N_NODES];

    const int tid  = threadIdx.x;
    const int lane = tid & 63;
    const int wave = tid >> 6;
    const int b    = blockIdx.x >> 8;                      // 256 blocks per batch
    const int i    = ((blockIdx.x & 255) * ROWS_PER_BLOCK) + wave;

    const size_t rowbase = ((size_t)b * N_NODES + i) * N_NODES;
    const float* Wr = W + rowbase;
    const float* Ar = alpha + rowbase;

    // ---- Issue first W/alpha tile BEFORE phase 1: global latency hides
    // under the table build + barrier instead of stalling the loop head.
    const int jfirst = lane * 4;
    float4 wc = *(const float4*)(Wr + jfirst);   // global_load_dwordx4
    float4 ac = *(const float4*)(Ar + jfirst);

    // ---- Phase 1: stage sin/cos(theta[b,:,:]) into LDS, bf16-packed ----
    const float* thb = theta + (size_t)b * (N_NODES * 4);
    #pragma unroll
    for (int g = 0; g < N_NODES / THREADS; ++g) {
        const int j = tid + g * THREADS;
        const float4 u = *(const float4*)(thb + (size_t)j * 4);  // coalesced
        const float th[4] = {u.x, u.y, u.z, u.w};
        #pragma unroll
        for (int d = 0; d < 4; ++d) {
            float s, c;
            __sincosf(th[d], &s, &c);
            tbl[d][j] = (bf16rn(c) << 16) | bf16rn(s);  // ds_write_b32, stride 4B: conflict-free
        }
    }
    __syncthreads();

    // ---- Phase 2: lane handles j0..j0+3 per iter; 8 iters per row ----
    //   im_d = sum_j (A*s_jd - B*c_jd),  re_d = sum_j (A*c_jd + B*s_jd)
    //   A = W*cos(alpha), B = W*sin(alpha)
    float re[4] = {0.f, 0.f, 0.f, 0.f};
    float im[4] = {0.f, 0.f, 0.f, 0.f};

    #pragma unroll
    for (int it = 0; it < N_NODES / 256; ++it) {
        const int j0 = it * 256 + lane * 4;

        // table tiles for current iter (4x ds_read_b128, conflict-free)
        const uint4 t0 = *(const uint4*)&tbl[0][j0];
        const uint4 t1 = *(const uint4*)&tbl[1][j0];
        const uint4 t2 = *(const uint4*)&tbl[2][j0];
        const uint4 t3 = *(const uint4*)&tbl[3][j0];

        // prefetch NEXT W/alpha tile (keeps >=2 iters = 4KB/wave in flight)
        float4 wn, an;
        if (it < N_NODES / 256 - 1) {
            wn = *(const float4*)(Wr + j0 + 256);
            an = *(const float4*)(Ar + j0 + 256);
        }

        const float wq[4] = {wc.x, wc.y, wc.z, wc.w};
        const float aq[4] = {ac.x, ac.y, ac.z, ac.w};
        float A[4], Bq[4];
        #pragma unroll
        for (int q = 0; q < 4; ++q) {
            float sa, ca;
            __sincosf(aq[q], &sa, &ca);
            A[q]  = wq[q] * ca;
            Bq[q] = wq[q] * sa;
        }

        #pragma unroll
        for (int d = 0; d < 4; ++d) {
            // compile-time select under full unroll -> stays in registers
            const uint4 t = (d == 0) ? t0 : (d == 1) ? t1 : (d == 2) ? t2 : t3;
            const uint32_t tu[4] = {t.x, t.y, t.z, t.w};
            #pragma unroll
            for (int q = 0; q < 4; ++q) {
                const float s = __uint_as_float(tu[q] << 16);
                const float c = __uint_as_float(tu[q] & 0xffff0000u);
                re[d] = fmaf(A[q],   c, re[d]);
                re[d] = fmaf(Bq[q],  s, re[d]);
                im[d] = fmaf(A[q],   s, im[d]);
                im[d] = fmaf(-Bq[q], c, im[d]);
            }
        }

        if (it < N_NODES / 256 - 1) { wc = wn; ac = an; }
    }

    // ---- Reduction: 6-stage butterfly over 64 lanes, 8 accumulators ----
    #pragma unroll
    for (int stage = 1; stage < 64; stage <<= 1) {
        #pragma unroll
        for (int d = 0; d < 4; ++d) {
            re[d] += __shfl_xor(re[d], stage, 64);
            im[d] += __shfl_xor(im[d], stage, 64);
        }
    }

    if (lane == 0) {
        const size_t obase = ((size_t)b * N_NODES + i) * 4;
        const float4 th4 = *(const float4*)(thb + (size_t)i * 4);
        const float4 g4  = *(const float4*)(gamma + obase);
        const float thd[4] = {th4.x, th4.y, th4.z, th4.w};
        const float gd[4]  = {g4.x, g4.y, g4.z, g4.w};
        float t[4];
        float s2 = 0.0f;
        #pragma unroll
        for (int d = 0; d < 4; ++d) {
            float s_i, c_i;
            __sincosf(thd[d], &s_i, &c_i);
            const float coup = (c_i * im[d] - s_i * re[d]) * (1.0f / (float)N_NODES);
            t[d] = gd[d] + coup;   // theta + (gamma-theta) + coupling  (DT=ATTR=1)
            s2 = fmaf(t[d], t[d], s2);
        }
        const float inv = 1.0f / fmaxf(sqrtf(s2), 1e-6f);
        *(float4*)(out + obase) = make_float4(t[0]*inv, t[1]*inv, t[2]*inv, t[3]*inv);
    }
}

extern "C" void kernel_launch(void* const* d_in, const int* in_sizes, int n_in,
                              void* d_out, int out_size, void* d_ws, size_t ws_size,
                              hipStream_t stream) {
    const float* theta = (const float*)d_in[0];
    const float* gamma = (const float*)d_in[1];
    const float* W     = (const float*)d_in[2];
    const float* alpha = (const float*)d_in[3];
    float* out = (float*)d_out;

    const int grid = (N_BATCH * N_NODES) / ROWS_PER_BLOCK;  // 1024 blocks = 4/CU
    hipLaunchKernelGGL(kuramoto_kernel, dim3(grid), dim3(THREADS), 0, stream,
                       theta, gamma, W, alpha, out);
}

// Round 2
// 150.610 us; speedup vs baseline: 1.1000x; 1.1000x over previous
//
#include <hip/hip_runtime.h>
#include <stdint.h>

#define N_NODES 2048
#define N_BATCH 4
#define ROWS_PER_BLOCK 8
#define THREADS 512   // 8 waves, one row per wave

__device__ __forceinline__ uint32_t bf16rn(float x) {
    uint32_t u = __float_as_uint(x);
    u += 0x7fffu + ((u >> 16) & 1u);
    return u >> 16;
}

// LDS = 32 KB table -> 4 blocks/CU (thread-cap), 32 waves/CU.
// __launch_bounds__(512, 8) -> VGPR cap 64.
// R1 lesson: full unroll + 4 simultaneous LDS tiles spilled (WRITE_SIZE 45 MB
// of scratch). This version keeps the x4-load + 1-deep prefetch pipeline but
// with a ROLLED loop and one LDS tile live at a time -> ~45 live VGPRs.
__global__ __launch_bounds__(THREADS, 8) void kuramoto_kernel(
    const float* __restrict__ theta,
    const float* __restrict__ gamma,
    const float* __restrict__ W,
    const float* __restrict__ alpha,
    float* __restrict__ out)
{
    // SoA by d: tbl[d][j] = (bf16(cos th_jd)<<16) | bf16(sin th_jd)
    // Lane owns 4 consecutive j -> per-d read is ds_read_b128 at lane
    // stride 16B = the conflict-free pattern.
    __shared__ uint32_t tbl[4][N_NODES];

    const int tid  = threadIdx.x;
    const int lane = tid & 63;
    const int wave = tid >> 6;
    const int b    = blockIdx.x >> 8;                      // 256 blocks per batch
    const int i    = ((blockIdx.x & 255) * ROWS_PER_BLOCK) + wave;

    const size_t rowbase = ((size_t)b * N_NODES + i) * N_NODES;
    const float* Wr = W + rowbase;
    const float* Ar = alpha + rowbase;

    // ---- Issue first W/alpha tile BEFORE phase 1: its latency hides under
    // the table build + barrier instead of stalling the loop head.
    const int jfirst = lane * 4;
    float4 wc = *(const float4*)(Wr + jfirst);   // global_load_dwordx4
    float4 ac = *(const float4*)(Ar + jfirst);

    // ---- Phase 1: stage sin/cos(theta[b,:,:]) into LDS, bf16-packed ----
    const float* thb = theta + (size_t)b * (N_NODES * 4);
    #pragma unroll
    for (int g = 0; g < N_NODES / THREADS; ++g) {
        const int j = tid + g * THREADS;
        const float4 u = *(const float4*)(thb + (size_t)j * 4);  // coalesced
        const float th[4] = {u.x, u.y, u.z, u.w};
        #pragma unroll
        for (int d = 0; d < 4; ++d) {
            float s, c;
            __sincosf(th[d], &s, &c);
            tbl[d][j] = (bf16rn(c) << 16) | bf16rn(s);  // stride 4B: conflict-free
        }
    }
    __syncthreads();

    // ---- Phase 2: rolled 1-deep pipeline; lane handles j0..j0+3 per iter ----
    //   im_d = sum_j (A*s_jd - B*c_jd),  re_d = sum_j (A*c_jd + B*s_jd)
    //   A = W*cos(alpha), B = W*sin(alpha)
    float re[4] = {0.f, 0.f, 0.f, 0.f};
    float im[4] = {0.f, 0.f, 0.f, 0.f};

    #define CONSUME(WV, AV, J0)                                              \
    do {                                                                     \
        const float wq_[4] = {(WV).x, (WV).y, (WV).z, (WV).w};               \
        const float aq_[4] = {(AV).x, (AV).y, (AV).z, (AV).w};               \
        float A_[4], Bq_[4];                                                 \
        _Pragma("unroll")                                                    \
        for (int q = 0; q < 4; ++q) {                                        \
            float sa_, ca_;                                                  \
            __sincosf(aq_[q], &sa_, &ca_);                                   \
            A_[q]  = wq_[q] * ca_;                                           \
            Bq_[q] = wq_[q] * sa_;                                           \
        }                                                                    \
        _Pragma("unroll")                                                    \
        for (int d = 0; d < 4; ++d) {                                        \
            const uint4 t_ = *(const uint4*)&tbl[d][(J0)];  /* one tile live */ \
            const uint32_t tu_[4] = {t_.x, t_.y, t_.z, t_.w};                \
            _Pragma("unroll")                                                \
            for (int q = 0; q < 4; ++q) {                                    \
                const float s_ = __uint_as_float(tu_[q] << 16);              \
                const float c_ = __uint_as_float(tu_[q] & 0xffff0000u);      \
                re[d] = fmaf(A_[q],   c_, re[d]);                            \
                re[d] = fmaf(Bq_[q],  s_, re[d]);                            \
                im[d] = fmaf(A_[q],   s_, im[d]);                            \
                im[d] = fmaf(-Bq_[q], c_, im[d]);                            \
            }                                                                \
        }                                                                    \
    } while (0)

    // steady state: issue next tile, consume current, rotate. Rolled so the
    // scheduler can't hoist all prefetches and re-create R1's spill.
    #pragma unroll 1
    for (int it = 0; it < N_NODES / 256 - 1; ++it) {
        const int j0 = it * 256 + lane * 4;
        const float4 wn = *(const float4*)(Wr + j0 + 256);
        const float4 an = *(const float4*)(Ar + j0 + 256);
        CONSUME(wc, ac, j0);
        wc = wn; ac = an;
    }
    CONSUME(wc, ac, (N_NODES / 256 - 1) * 256 + lane * 4);  // epilogue
    #undef CONSUME

    // ---- Reduction: 6-stage butterfly over 64 lanes, 8 accumulators ----
    #pragma unroll
    for (int stage = 1; stage < 64; stage <<= 1) {
        #pragma unroll
        for (int d = 0; d < 4; ++d) {
            re[d] += __shfl_xor(re[d], stage, 64);
            im[d] += __shfl_xor(im[d], stage, 64);
        }
    }

    if (lane == 0) {
        const size_t obase = ((size_t)b * N_NODES + i) * 4;
        const float4 th4 = *(const float4*)(thb + (size_t)i * 4);
        const float4 g4  = *(const float4*)(gamma + obase);
        const float thd[4] = {th4.x, th4.y, th4.z, th4.w};
        const float gd[4]  = {g4.x, g4.y, g4.z, g4.w};
        float t[4];
        float s2 = 0.0f;
        #pragma unroll
        for (int d = 0; d < 4; ++d) {
            float s_i, c_i;
            __sincosf(thd[d], &s_i, &c_i);
            const float coup = (c_i * im[d] - s_i * re[d]) * (1.0f / (float)N_NODES);
            t[d] = gd[d] + coup;   // theta + (gamma-theta) + coupling  (DT=ATTR=1)
            s2 = fmaf(t[d], t[d], s2);
        }
        const float inv = 1.0f / fmaxf(sqrtf(s2), 1e-6f);
        *(float4*)(out + obase) = make_float4(t[0]*inv, t[1]*inv, t[2]*inv, t[3]*inv);
    }
}

extern "C" void kernel_launch(void* const* d_in, const int* in_sizes, int n_in,
                              void* d_out, int out_size, void* d_ws, size_t ws_size,
                              hipStream_t stream) {
    const float* theta = (const float*)d_in[0];
    const float* gamma = (const float*)d_in[1];
    const float* W     = (const float*)d_in[2];
    const float* alpha = (const float*)d_in[3];
    float* out = (float*)d_out;

    const int grid = (N_BATCH * N_NODES) / ROWS_PER_BLOCK;  // 1024 blocks = 4/CU
    hipLaunchKernelGGL(kuramoto_kernel, dim3(grid), dim3(THREADS), 0, stream,
                       theta, gamma, W, alpha, out);
}